// Round 1
// baseline (1277.392 us; speedup 1.0000x reference)
//
#include <hip/hip_runtime.h>

#define NSAMP   480000
#define NFRAMES 3000
#define NFFT    400
#define NFREQ   201
#define NMELS   80
#define HOP     160
#define BATCH   64
#define TT      32
#define SPAN    ((TT - 1) * HOP + NFFT)          // 5360
#define TBLK    ((NFRAMES + TT - 1) / TT)        // 94
#define FEAT_ELEMS (BATCH * NMELS * NFRAMES)     // 15,360,000
#define OUT_ELEMS  (FEAT_ELEMS + BATCH * NFRAMES)// 15,552,000
#define TWO_PI  6.283185307179586f

// ws layout (floats): [0, 80400) wrT  | [80400, 160800) wiT | [160800, +64) wmax keys

__global__ __launch_bounds__(256)
void fill_weights_k(float* __restrict__ wrT, float* __restrict__ wiT,
                    unsigned* __restrict__ wmax) {
    int i = blockIdx.x * 256 + threadIdx.x;
    if (i < NFFT * NFREQ) {
        int n = i / NFREQ;
        int k = i - n * NFREQ;
        float win = 0.5f - 0.5f * cosf(TWO_PI * (float)n / (float)NFFT);
        int r = (k * n) % NFFT;                      // exact angle reduction
        float ph = (float)r * (TWO_PI / (float)NFFT);
        float sv, cv;
        sincosf(ph, &sv, &cv);
        wrT[i] = cv * win;        // wrT[n*201 + k]
        wiT[i] = -sv * win;
    }
    if (blockIdx.x == 0 && threadIdx.x < BATCH) wmax[threadIdx.x] = 0u;
}

__global__ __launch_bounds__(256)
void stft_mel_k(const float* __restrict__ wav, const float* __restrict__ mf,
                const float* __restrict__ wrT, const float* __restrict__ wiT,
                float* __restrict__ out, unsigned* __restrict__ wmax) {
    __shared__ __align__(16) float span[SPAN];
    __shared__ float pw[NFREQ][TT + 1];
    __shared__ float red[256];

    const int b  = blockIdx.y;
    const int t0 = blockIdx.x * TT;
    const float* w = wav + (size_t)b * NSAMP;
    const int g0 = t0 * HOP - (NFFT / 2);

    // Stage overlapping frame span with inline reflect padding.
    for (int i = threadIdx.x; i < SPAN; i += 256) {
        int idx = g0 + i;
        idx = (idx < 0) ? -idx : idx;
        idx = (idx >= NSAMP) ? (2 * NSAMP - 2 - idx) : idx;
        span[i] = w[idx];
    }
    __syncthreads();

    // STFT: thread k computes re/im for 32 frames. span reads are wave-broadcast.
    const int k = threadIdx.x;
    if (k < NFREQ) {
        float re[TT], im[TT];
        #pragma unroll
        for (int t = 0; t < TT; ++t) { re[t] = 0.f; im[t] = 0.f; }
        for (int n = 0; n < NFFT; n += 4) {
            const float wr0 = wrT[(n + 0) * NFREQ + k];
            const float wr1 = wrT[(n + 1) * NFREQ + k];
            const float wr2 = wrT[(n + 2) * NFREQ + k];
            const float wr3 = wrT[(n + 3) * NFREQ + k];
            const float wi0 = wiT[(n + 0) * NFREQ + k];
            const float wi1 = wiT[(n + 1) * NFREQ + k];
            const float wi2 = wiT[(n + 2) * NFREQ + k];
            const float wi3 = wiT[(n + 3) * NFREQ + k];
            #pragma unroll
            for (int t = 0; t < TT; ++t) {
                const float4 s = *reinterpret_cast<const float4*>(&span[t * HOP + n]);
                re[t] = fmaf(wr0, s.x, re[t]);
                im[t] = fmaf(wi0, s.x, im[t]);
                re[t] = fmaf(wr1, s.y, re[t]);
                im[t] = fmaf(wi1, s.y, im[t]);
                re[t] = fmaf(wr2, s.z, re[t]);
                im[t] = fmaf(wi2, s.z, im[t]);
                re[t] = fmaf(wr3, s.w, re[t]);
                im[t] = fmaf(wi3, s.w, im[t]);
            }
        }
        #pragma unroll
        for (int t = 0; t < TT; ++t) pw[k][t] = re[t] * re[t] + im[t] * im[t];
    }
    __syncthreads();

    // Mel projection: thread (t = tid&31, mg = tid>>5) computes 10 mel bins.
    const int t  = threadIdx.x & 31;
    const int mg = threadIdx.x >> 5;
    float acc[10];
    #pragma unroll
    for (int j = 0; j < 10; ++j) acc[j] = 0.f;
    for (int kk = 0; kk < NFREQ; ++kk) {
        const float p = pw[kk][t];
        const float* mrow = mf + kk * NMELS + mg * 10;
        #pragma unroll
        for (int j = 0; j < 10; ++j) acc[j] = fmaf(p, mrow[j], acc[j]);
    }

    float lmax = -3.0e38f;
    const int tt = t0 + t;
    if (tt < NFRAMES) {
        #pragma unroll
        for (int j = 0; j < 10; ++j) {
            float v = log10f(fmaxf(acc[j], 1e-10f));
            out[(size_t)b * (NMELS * NFRAMES) + (size_t)(mg * 10 + j) * NFRAMES + tt] = v;
            lmax = fmaxf(lmax, v);
        }
    }

    // Block max -> per-batch atomic max (monotonic unsigned key encoding).
    red[threadIdx.x] = lmax;
    __syncthreads();
    for (int s = 128; s > 0; s >>= 1) {
        if (threadIdx.x < s) red[threadIdx.x] = fmaxf(red[threadIdx.x], red[threadIdx.x + s]);
        __syncthreads();
    }
    if (threadIdx.x == 0) {
        unsigned bits = __float_as_uint(red[0]);
        unsigned key = bits ^ ((bits & 0x80000000u) ? 0xFFFFFFFFu : 0x80000000u);
        atomicMax(&wmax[b], key);
    }
}

__global__ __launch_bounds__(256)
void finalize_k(float* __restrict__ out, const unsigned* __restrict__ wmax,
                const int* __restrict__ valid) {
    const int i = blockIdx.x * 256 + threadIdx.x;
    if (i < FEAT_ELEMS) {
        const int b = i / (NMELS * NFRAMES);
        const unsigned key = wmax[b];
        const unsigned bits = key ^ ((key & 0x80000000u) ? 0x80000000u : 0xFFFFFFFFu);
        const float mx = __uint_as_float(bits);
        float v = out[i];
        v = fmaxf(v, mx - 8.0f);
        out[i] = (v + 4.0f) * 0.25f;
    } else if (i < OUT_ELEMS) {
        const int j = i - FEAT_ELEMS;
        const int bb = j / NFRAMES;
        const int tf = j - bb * NFRAMES;
        out[i] = (tf * HOP < valid[bb]) ? 1.0f : 0.0f;
    }
}

extern "C" void kernel_launch(void* const* d_in, const int* in_sizes, int n_in,
                              void* d_out, int out_size, void* d_ws, size_t ws_size,
                              hipStream_t stream) {
    const float* wav   = (const float*)d_in[0];
    const int*   valid = (const int*)d_in[1];
    const float* mf    = (const float*)d_in[2];
    float* out = (float*)d_out;

    float* wrT = (float*)d_ws;
    float* wiT = wrT + NFFT * NFREQ;
    unsigned* wmax = (unsigned*)(wiT + NFFT * NFREQ);

    fill_weights_k<<<(NFFT * NFREQ + 255) / 256, 256, 0, stream>>>(wrT, wiT, wmax);
    dim3 g(TBLK, BATCH);
    stft_mel_k<<<g, 256, 0, stream>>>(wav, mf, wrT, wiT, out, wmax);
    finalize_k<<<(OUT_ELEMS + 255) / 256, 256, 0, stream>>>(out, wmax, valid);
}

// Round 2
// 550.354 us; speedup vs baseline: 2.3210x; 2.3210x over previous
//
#include <hip/hip_runtime.h>
#include <hip/hip_bf16.h>

#define NSAMP   480000
#define NFRAMES 3000
#define NFFT    400
#define NFREQ   201
#define NMELS   80
#define HOP     160
#define BATCH   64
#define TT      32
#define TBLK    ((NFRAMES + TT - 1) / TT)        // 94
#define SPAN2   5376                             // staged bf16 samples per block
#define NFRAG   26                               // ceil(402/16)
#define KSTEPS  13                               // ceil(400/32)
#define FEAT_ELEMS (BATCH * NMELS * NFRAMES)     // 15,360,000
#define OUT_ELEMS  (FEAT_ELEMS + BATCH * NFRAMES)
#define TWO_PI  6.283185307179586f
#define WFRAG_BYTES (NFRAG * KSTEPS * 64 * 8 * 2)  // 346,112

typedef __attribute__((ext_vector_type(8))) short bf16x8;
typedef __attribute__((ext_vector_type(4))) float f32x4;

static __device__ __forceinline__ ushort f2bf(float x) {
    __hip_bfloat16 h = __float2bfloat16(x);
    return *reinterpret_cast<ushort*>(&h);
}

// B-fragment table: wf[((nf*13+ks)*64+lane)*8 + j] = W[k][n] (bf16),
// n = nf*16 + (lane&15) (even n: re row f=n/2, odd: im), k = ks*32 + 8*(lane>>4) + j.
__global__ __launch_bounds__(256)
void fill_wfrag_k(ushort* __restrict__ wf, unsigned* __restrict__ wmax) {
    int t = blockIdx.x * 256 + threadIdx.x;
    if (t < NFRAG * KSTEPS * 64) {
        const int lane = t & 63;
        const int fk = t >> 6;
        const int ks = fk % KSTEPS;
        const int nf = fk / KSTEPS;
        const int n = nf * 16 + (lane & 15);
        const int kbase = ks * 32 + 8 * (lane >> 4);
        #pragma unroll
        for (int j = 0; j < 8; ++j) {
            const int k = kbase + j;
            float val = 0.f;
            if (n < 2 * NFREQ && k < NFFT) {
                const int f = n >> 1;
                const float win = 0.5f - 0.5f * cosf(TWO_PI * (float)k / (float)NFFT);
                const int r = (f * k) % NFFT;              // exact angle reduction
                const float ph = (float)r * (TWO_PI / (float)NFFT);
                float sv, cv;
                sincosf(ph, &sv, &cv);
                val = (n & 1) ? (-sv * win) : (cv * win);
            }
            wf[(size_t)t * 8 + j] = f2bf(val);
        }
    }
    if (blockIdx.x == 0 && threadIdx.x < BATCH) wmax[threadIdx.x] = 0u;
}

__global__ __launch_bounds__(256)
void stft_mel_mfma_k(const float* __restrict__ wav, const float* __restrict__ mf,
                     const ushort* __restrict__ wfrag,
                     float* __restrict__ out, unsigned* __restrict__ wmax) {
    __shared__ __align__(16) ushort span[SPAN2];
    __shared__ float pw[NFREQ][TT + 1];
    __shared__ float red[256];

    const int b  = blockIdx.y;
    const int t0 = blockIdx.x * TT;
    const float* w = wav + (size_t)b * NSAMP;
    const int g0 = t0 * HOP - (NFFT / 2);

    // Stage overlapped frame span as bf16, inline reflect padding.
    #pragma unroll
    for (int j = 0; j < SPAN2 / 256; ++j) {
        const int i = threadIdx.x + j * 256;
        int idx = g0 + i;
        idx = (idx < 0) ? -idx : idx;
        idx = (idx >= NSAMP) ? (2 * NSAMP - 2 - idx) : idx;
        span[i] = f2bf(w[idx]);
    }
    __syncthreads();

    const int l  = threadIdx.x & 63;
    const int wv = threadIdx.x >> 6;
    const int nfr = (wv < 2) ? 7 : 6;   // waves 0,1: 7 N-frags; 2,3: 6  (covers nf 0..25)

    f32x4 acc[7][2];
    #pragma unroll
    for (int i = 0; i < 7; ++i)
        #pragma unroll
        for (int m = 0; m < 2; ++m)
            acc[i][m] = (f32x4){0.f, 0.f, 0.f, 0.f};

    // A-fragment base (ushort units): row m=(l&15)+16*mf, k-offset 8*(l>>4)+32*ks
    const ushort* aB = span + (l & 15) * HOP + 8 * (l >> 4);

    for (int ks = 0; ks < KSTEPS; ++ks) {
        const bf16x8 a0 = *reinterpret_cast<const bf16x8*>(aB + ks * 32);
        const bf16x8 a1 = *reinterpret_cast<const bf16x8*>(aB + 16 * HOP + ks * 32);
        #pragma unroll
        for (int i = 0; i < 7; ++i) {
            if (i < nfr) {
                const int nf = wv + 4 * i;
                const bf16x8 bf = *reinterpret_cast<const bf16x8*>(
                    wfrag + ((size_t)(nf * KSTEPS + ks) * 64 + l) * 8);
                acc[i][0] = __builtin_amdgcn_mfma_f32_16x16x32_bf16(a0, bf, acc[i][0], 0, 0, 0);
                acc[i][1] = __builtin_amdgcn_mfma_f32_16x16x32_bf16(a1, bf, acc[i][1], 0, 0, 0);
            }
        }
    }

    // power = re^2 + im^2 ; re/im live in adjacent lanes (even/odd N columns).
    #pragma unroll
    for (int i = 0; i < 7; ++i) {
        if (i < nfr) {
            const int nf = wv + 4 * i;
            #pragma unroll
            for (int m = 0; m < 2; ++m) {
                const f32x4 v = acc[i][m];
                #pragma unroll
                for (int r = 0; r < 4; ++r) {
                    float p = v[r] * v[r];
                    p += __shfl_xor(p, 1);
                    if (!(l & 1)) {
                        const int f = 8 * nf + ((l & 15) >> 1);
                        const int frame = m * 16 + 4 * (l >> 4) + r;
                        if (f < NFREQ) pw[f][frame] = p;
                    }
                }
            }
        }
    }
    __syncthreads();

    // Mel projection: thread (t = tid&31, mg = tid>>5) computes 10 mel bins.
    const int t  = threadIdx.x & 31;
    const int mg = threadIdx.x >> 5;
    float macc[10];
    #pragma unroll
    for (int j = 0; j < 10; ++j) macc[j] = 0.f;
    for (int kk = 0; kk < NFREQ; ++kk) {
        const float p = pw[kk][t];
        const float* mrow = mf + kk * NMELS + mg * 10;
        #pragma unroll
        for (int j = 0; j < 10; ++j) macc[j] = fmaf(p, mrow[j], macc[j]);
    }

    float lmax = -3.0e38f;
    const int tt = t0 + t;
    if (tt < NFRAMES) {
        #pragma unroll
        for (int j = 0; j < 10; ++j) {
            float v = log10f(fmaxf(macc[j], 1e-10f));
            out[(size_t)b * (NMELS * NFRAMES) + (size_t)(mg * 10 + j) * NFRAMES + tt] = v;
            lmax = fmaxf(lmax, v);
        }
    }

    red[threadIdx.x] = lmax;
    __syncthreads();
    for (int s = 128; s > 0; s >>= 1) {
        if (threadIdx.x < s) red[threadIdx.x] = fmaxf(red[threadIdx.x], red[threadIdx.x + s]);
        __syncthreads();
    }
    if (threadIdx.x == 0) {
        unsigned bits = __float_as_uint(red[0]);
        unsigned key = bits ^ ((bits & 0x80000000u) ? 0xFFFFFFFFu : 0x80000000u);
        atomicMax(&wmax[b], key);
    }
}

__global__ __launch_bounds__(256)
void finalize_k(float* __restrict__ out, const unsigned* __restrict__ wmax,
                const int* __restrict__ valid) {
    const int i = blockIdx.x * 256 + threadIdx.x;
    if (i < FEAT_ELEMS) {
        const int b = i / (NMELS * NFRAMES);
        const unsigned key = wmax[b];
        const unsigned bits = key ^ ((key & 0x80000000u) ? 0x80000000u : 0xFFFFFFFFu);
        const float mx = __uint_as_float(bits);
        float v = out[i];
        v = fmaxf(v, mx - 8.0f);
        out[i] = (v + 4.0f) * 0.25f;
    } else if (i < OUT_ELEMS) {
        const int j = i - FEAT_ELEMS;
        const int bb = j / NFRAMES;
        const int tf = j - bb * NFRAMES;
        out[i] = (tf * HOP < valid[bb]) ? 1.0f : 0.0f;
    }
}

extern "C" void kernel_launch(void* const* d_in, const int* in_sizes, int n_in,
                              void* d_out, int out_size, void* d_ws, size_t ws_size,
                              hipStream_t stream) {
    const float* wav   = (const float*)d_in[0];
    const int*   valid = (const int*)d_in[1];
    const float* mf    = (const float*)d_in[2];
    float* out = (float*)d_out;

    ushort*   wfrag = (ushort*)d_ws;
    unsigned* wmax  = (unsigned*)((char*)d_ws + WFRAG_BYTES);

    fill_wfrag_k<<<(NFRAG * KSTEPS * 64 + 255) / 256, 256, 0, stream>>>(wfrag, wmax);
    dim3 g(TBLK, BATCH);
    stft_mel_mfma_k<<<g, 256, 0, stream>>>(wav, mf, wfrag, out, wmax);
    finalize_k<<<(OUT_ELEMS + 255) / 256, 256, 0, stream>>>(out, wmax, valid);
}

// Round 3
// 333.181 us; speedup vs baseline: 3.8339x; 1.6518x over previous
//
#include <hip/hip_runtime.h>
#include <hip/hip_bf16.h>

#define NSAMP   480000
#define NFRAMES 3000
#define NFFT    400
#define NFREQ   201
#define NMELS   80
#define HOP     160
#define BATCH   64
#define TT      32
#define TBLK    94
#define SPAN2   5376
#define NFRAG   26
#define KSTEPS  13
#define MKSTEPS 7                                 // mel K-steps (K padded to 224)
#define PWS     232                               // pw row stride in ushorts (464B: 16B-aligned, ~2-way banks)
#define FEAT_ELEMS (BATCH * NMELS * NFRAMES)
#define OUT_ELEMS  (FEAT_ELEMS + BATCH * NFRAMES)
#define TWO_PI  6.283185307179586f
#define WFRAG_ELEMS (NFRAG * KSTEPS * 64 * 8)     // 173056
#define MFRAG_ELEMS (5 * MKSTEPS * 64 * 8)        // 17920
#define WFRAG_BYTES (WFRAG_ELEMS * 2)
#define MFRAG_BYTES (MFRAG_ELEMS * 2)

typedef __attribute__((ext_vector_type(8))) short bf16x8;
typedef __attribute__((ext_vector_type(4))) float f32x4;

static __device__ __forceinline__ ushort f2bf(float x) {
    __hip_bfloat16 h = __float2bfloat16(x);
    return *reinterpret_cast<ushort*>(&h);
}

// wfrag: B-frags of DFT matrix W[k][n]; n=nf*16+(l&15) (even n: cos, odd: -sin), k=ks*32+8*(l>>4)+j.
// mfrag: A-frags of MF^T: row mel=Mf*16+(l&15), k=freq=ks*32+8*(l>>4)+j, val=mf[freq*80+mel].
__global__ __launch_bounds__(256)
void fill_tables_k(ushort* __restrict__ wf, ushort* __restrict__ mfr,
                   const float* __restrict__ mf, unsigned* __restrict__ wmax) {
    const int t = blockIdx.x * 256 + threadIdx.x;
    if (t < WFRAG_ELEMS / 8) {
        const int lane = t & 63;
        const int fk = t >> 6;
        const int ks = fk % KSTEPS;
        const int nf = fk / KSTEPS;
        const int n = nf * 16 + (lane & 15);
        const int kbase = ks * 32 + 8 * (lane >> 4);
        #pragma unroll
        for (int j = 0; j < 8; ++j) {
            const int k = kbase + j;
            float val = 0.f;
            if (n < 2 * NFREQ && k < NFFT) {
                const int f = n >> 1;
                const float win = 0.5f - 0.5f * cosf(TWO_PI * (float)k / (float)NFFT);
                const int r = (f * k) % NFFT;
                const float ph = (float)r * (TWO_PI / (float)NFFT);
                float sv, cv;
                sincosf(ph, &sv, &cv);
                val = (n & 1) ? (-sv * win) : (cv * win);
            }
            wf[(size_t)t * 8 + j] = f2bf(val);
        }
    } else if (t < WFRAG_ELEMS / 8 + MFRAG_ELEMS / 8) {
        const int u = t - WFRAG_ELEMS / 8;
        const int lane = u & 63;
        const int fk = u >> 6;
        const int ks = fk % MKSTEPS;
        const int Mf = fk / MKSTEPS;
        const int mel = Mf * 16 + (lane & 15);
        const int kbase = ks * 32 + 8 * (lane >> 4);
        #pragma unroll
        for (int j = 0; j < 8; ++j) {
            const int freq = kbase + j;
            const float val = (freq < NFREQ) ? mf[freq * NMELS + mel] : 0.f;
            mfr[(size_t)u * 8 + j] = f2bf(val);
        }
    }
    if (blockIdx.x == 0 && threadIdx.x < BATCH) wmax[threadIdx.x] = 0u;
}

__global__ __launch_bounds__(256, 6)
void stft_mel_mfma_k(const float* __restrict__ wav, const ushort* __restrict__ wfrag,
                     const ushort* __restrict__ mfrag,
                     float* __restrict__ out, unsigned* __restrict__ wmax) {
    __shared__ __align__(16) ushort span[SPAN2];
    __shared__ __align__(16) ushort pw[TT * PWS];

    const int b  = blockIdx.y;
    const int t0 = blockIdx.x * TT;
    const float* w = wav + (size_t)b * NSAMP;
    const int g0 = t0 * HOP - (NFFT / 2);

    // Zero the K-padding columns (freq 201..231) of pw.
    for (int i = threadIdx.x; i < TT * 31; i += 256) {
        const int row = i / 31;
        const int c = 201 + i - row * 31;
        pw[row * PWS + c] = 0;
    }
    // Stage overlapped span as bf16 with inline reflect padding.
    #pragma unroll
    for (int j = 0; j < SPAN2 / 256; ++j) {
        const int i = threadIdx.x + j * 256;
        int idx = g0 + i;
        idx = (idx < 0) ? -idx : idx;
        idx = (idx >= NSAMP) ? (2 * NSAMP - 2 - idx) : idx;
        span[i] = f2bf(w[idx]);
    }
    __syncthreads();

    const int l  = threadIdx.x & 63;
    const int wv = threadIdx.x >> 6;
    const int nfr = (wv < 2) ? 7 : 6;

    f32x4 acc[7][2];
    #pragma unroll
    for (int i = 0; i < 7; ++i)
        #pragma unroll
        for (int m = 0; m < 2; ++m)
            acc[i][m] = (f32x4){0.f, 0.f, 0.f, 0.f};

    const ushort* aB = span + (l & 15) * HOP + 8 * (l >> 4);

    for (int ks = 0; ks < KSTEPS; ++ks) {
        const bf16x8 a0 = *reinterpret_cast<const bf16x8*>(aB + ks * 32);
        const bf16x8 a1 = *reinterpret_cast<const bf16x8*>(aB + 16 * HOP + ks * 32);
        #pragma unroll
        for (int i = 0; i < 7; ++i) {
            if (i < nfr) {
                const int nf = wv + 4 * i;
                const bf16x8 bf = *reinterpret_cast<const bf16x8*>(
                    wfrag + ((size_t)(nf * KSTEPS + ks) * 64 + l) * 8);
                acc[i][0] = __builtin_amdgcn_mfma_f32_16x16x32_bf16(a0, bf, acc[i][0], 0, 0, 0);
                acc[i][1] = __builtin_amdgcn_mfma_f32_16x16x32_bf16(a1, bf, acc[i][1], 0, 0, 0);
            }
        }
    }

    // power = re^2+im^2 (adjacent lanes), scatter to pw[frame][freq] as bf16.
    #pragma unroll
    for (int i = 0; i < 7; ++i) {
        if (i < nfr) {
            const int nf = wv + 4 * i;
            #pragma unroll
            for (int m = 0; m < 2; ++m) {
                const f32x4 v = acc[i][m];
                #pragma unroll
                for (int r = 0; r < 4; ++r) {
                    float p = v[r] * v[r];
                    p += __shfl_xor(p, 1);
                    if (!(l & 1)) {
                        const int f = 8 * nf + ((l & 15) >> 1);
                        const int frame = 16 * m + 4 * (l >> 4) + r;
                        if (f < NFREQ) pw[frame * PWS + f] = f2bf(p);
                    }
                }
            }
        }
    }
    __syncthreads();

    // Mel GEMM: D[mel][frame] = MF^T x P^T. Wave Mf sets: w0:{0,4}, w1:{1}, w2:{2}, w3:{3}.
    float lmax = -3.0e38f;
    const int nmf = (wv == 0) ? 2 : 1;
    #pragma unroll
    for (int q = 0; q < 2; ++q) {
        if (q < nmf) {
            const int Mf = wv + 4 * q;
            f32x4 mc[2];
            mc[0] = (f32x4){0.f, 0.f, 0.f, 0.f};
            mc[1] = (f32x4){0.f, 0.f, 0.f, 0.f};
            for (int ks = 0; ks < MKSTEPS; ++ks) {
                const bf16x8 aT = *reinterpret_cast<const bf16x8*>(
                    mfrag + ((size_t)(Mf * MKSTEPS + ks) * 64 + l) * 8);
                const bf16x8 b0 = *reinterpret_cast<const bf16x8*>(
                    pw + (l & 15) * PWS + 8 * (l >> 4) + 32 * ks);
                const bf16x8 b1 = *reinterpret_cast<const bf16x8*>(
                    pw + ((l & 15) + 16) * PWS + 8 * (l >> 4) + 32 * ks);
                mc[0] = __builtin_amdgcn_mfma_f32_16x16x32_bf16(aT, b0, mc[0], 0, 0, 0);
                mc[1] = __builtin_amdgcn_mfma_f32_16x16x32_bf16(aT, b1, mc[1], 0, 0, 0);
            }
            #pragma unroll
            for (int nf2 = 0; nf2 < 2; ++nf2) {
                #pragma unroll
                for (int r = 0; r < 4; ++r) {
                    const int mel = Mf * 16 + 4 * (l >> 4) + r;
                    const int frame = t0 + nf2 * 16 + (l & 15);
                    if (frame < NFRAMES) {
                        const float v = log10f(fmaxf(mc[nf2][r], 1e-10f));
                        out[((size_t)b * NMELS + mel) * NFRAMES + frame] = v;
                        lmax = fmaxf(lmax, v);
                    }
                }
            }
        }
    }

    // Wave-level max reduce -> one atomic per wave.
    #pragma unroll
    for (int off = 32; off > 0; off >>= 1)
        lmax = fmaxf(lmax, __shfl_xor(lmax, off));
    if (l == 0) {
        const unsigned bits = __float_as_uint(lmax);
        const unsigned key = bits ^ ((bits & 0x80000000u) ? 0xFFFFFFFFu : 0x80000000u);
        atomicMax(&wmax[b], key);
    }
}

__global__ __launch_bounds__(256)
void finalize_k(float* __restrict__ out, const unsigned* __restrict__ wmax,
                const int* __restrict__ valid) {
    const int i = blockIdx.x * 256 + threadIdx.x;
    if (i < FEAT_ELEMS) {
        const int b = i / (NMELS * NFRAMES);
        const unsigned key = wmax[b];
        const unsigned bits = key ^ ((key & 0x80000000u) ? 0x80000000u : 0xFFFFFFFFu);
        const float mx = __uint_as_float(bits);
        float v = out[i];
        v = fmaxf(v, mx - 8.0f);
        out[i] = (v + 4.0f) * 0.25f;
    } else if (i < OUT_ELEMS) {
        const int j = i - FEAT_ELEMS;
        const int bb = j / NFRAMES;
        const int tf = j - bb * NFRAMES;
        out[i] = (tf * HOP < valid[bb]) ? 1.0f : 0.0f;
    }
}

extern "C" void kernel_launch(void* const* d_in, const int* in_sizes, int n_in,
                              void* d_out, int out_size, void* d_ws, size_t ws_size,
                              hipStream_t stream) {
    const float* wav   = (const float*)d_in[0];
    const int*   valid = (const int*)d_in[1];
    const float* mf    = (const float*)d_in[2];
    float* out = (float*)d_out;

    ushort*   wfrag = (ushort*)d_ws;
    ushort*   mfrag = (ushort*)((char*)d_ws + WFRAG_BYTES);
    unsigned* wmax  = (unsigned*)((char*)d_ws + WFRAG_BYTES + MFRAG_BYTES);

    const int fill_items = WFRAG_ELEMS / 8 + MFRAG_ELEMS / 8;
    fill_tables_k<<<(fill_items + 255) / 256, 256, 0, stream>>>(wfrag, mfrag, mf, wmax);
    dim3 g(TBLK, BATCH);
    stft_mel_mfma_k<<<g, 256, 0, stream>>>(wav, wfrag, mfrag, out, wmax);
    finalize_k<<<(OUT_ELEMS + 255) / 256, 256, 0, stream>>>(out, wmax, valid);
}

// Round 4
// 271.245 us; speedup vs baseline: 4.7094x; 1.2283x over previous
//
#include <hip/hip_runtime.h>
#include <hip/hip_bf16.h>

#define NSAMP   480000
#define NFRAMES 3000
#define NFFT    400
#define NFREQ   201
#define NMELS   80
#define HOP     160
#define BATCH   64
#define TT      64
#define TBLK    47                                // ceil(3000/64)
#define SPANU   10496                             // (TT-1)*HOP + 416 (padded K) bf16 samples
#define NFRAG   26
#define KSTEPS  13
#define MKSTEPS 7
#define PWS     232                               // pw row stride (ushorts); 29 16B-slots (odd) -> conflict-free
#define BCHUNK  512                               // ushorts per nf-chunk (64 lanes x 8)
#define BTILE   (NFRAG * BCHUNK)                  // 13312 ushorts per B K-tile
#define LDS_B0  SPANU
#define LDS_PW  SPANU                             // pw aliases the B double-buffer region
#define LDS_TOT (SPANU + 2 * BTILE)               // 37120 ushorts = 74240 B
#define FEAT_ELEMS (BATCH * NMELS * NFRAMES)
#define OUT_ELEMS  (FEAT_ELEMS + BATCH * NFRAMES)
#define TWO_PI  6.283185307179586f
#define WFRAG_ELEMS (NFRAG * KSTEPS * 64 * 8)     // 173056
#define MFRAG_ELEMS (5 * MKSTEPS * 64 * 8)        // 17920
#define WFRAG_BYTES (WFRAG_ELEMS * 2)
#define MFRAG_BYTES (MFRAG_ELEMS * 2)

typedef __attribute__((ext_vector_type(8))) short bf16x8;
typedef __attribute__((ext_vector_type(4))) float f32x4;

static __device__ __forceinline__ ushort f2bf(float x) {
    __hip_bfloat16 h = __float2bfloat16(x);
    return *reinterpret_cast<ushort*>(&h);
}

// async global->LDS, 16B per lane; LDS dest is wave-uniform base + lane*16 (HW).
static __device__ __forceinline__ void gld16(const ushort* g, ushort* l) {
    __builtin_amdgcn_global_load_lds(
        (const __attribute__((address_space(1))) unsigned int*)g,
        (__attribute__((address_space(3))) unsigned int*)l, 16, 0, 0);
}

// wfrag: B-frags of DFT W[k][n]; n=nf*16+(l&15) (even n: cos f=n/2, odd: -sin), k=ks*32+8*(l>>4)+j.
// mfrag: A-frags of MF^T: mel=Mf*16+(l&15), k=freq=ks*32+8*(l>>4)+j.
__global__ __launch_bounds__(256)
void fill_tables_k(ushort* __restrict__ wf, ushort* __restrict__ mfr,
                   const float* __restrict__ mf, unsigned* __restrict__ wmax) {
    const int t = blockIdx.x * 256 + threadIdx.x;
    if (t < WFRAG_ELEMS / 8) {
        const int lane = t & 63;
        const int fk = t >> 6;
        const int ks = fk % KSTEPS;
        const int nf = fk / KSTEPS;
        const int n = nf * 16 + (lane & 15);
        const int kbase = ks * 32 + 8 * (lane >> 4);
        #pragma unroll
        for (int j = 0; j < 8; ++j) {
            const int k = kbase + j;
            float val = 0.f;
            if (n < 2 * NFREQ && k < NFFT) {
                const int f = n >> 1;
                const float win = 0.5f - 0.5f * cosf(TWO_PI * (float)k / (float)NFFT);
                const int r = (f * k) % NFFT;
                const float ph = (float)r * (TWO_PI / (float)NFFT);
                float sv, cv;
                sincosf(ph, &sv, &cv);
                val = (n & 1) ? (-sv * win) : (cv * win);
            }
            wf[(size_t)t * 8 + j] = f2bf(val);
        }
    } else if (t < WFRAG_ELEMS / 8 + MFRAG_ELEMS / 8) {
        const int u = t - WFRAG_ELEMS / 8;
        const int lane = u & 63;
        const int fk = u >> 6;
        const int ks = fk % MKSTEPS;
        const int Mf = fk / MKSTEPS;
        const int mel = Mf * 16 + (lane & 15);
        const int kbase = ks * 32 + 8 * (lane >> 4);
        #pragma unroll
        for (int j = 0; j < 8; ++j) {
            const int freq = kbase + j;
            const float val = (freq < NFREQ) ? mf[freq * NMELS + mel] : 0.f;
            mfr[(size_t)u * 8 + j] = f2bf(val);
        }
    }
    if (blockIdx.x == 0 && threadIdx.x < BATCH) wmax[threadIdx.x] = 0u;
}

static __device__ __forceinline__ void stageB(const ushort* __restrict__ wfrag,
                                              ushort* ldsB, int ks, int wv, int l) {
    #pragma unroll
    for (int j = 0; j < 4; ++j) {
        const int c = wv + 8 * j;                  // wave-uniform chunk id
        if (c < NFRAG)
            gld16(wfrag + ((size_t)(c * KSTEPS + ks) << 9) + (l << 3),
                  ldsB + c * BCHUNK);
    }
}

__global__ __launch_bounds__(512, 4)
void stft_mel_mfma_k(const float* __restrict__ wav, const ushort* __restrict__ wfrag,
                     const ushort* __restrict__ mfrag,
                     float* __restrict__ out, unsigned* __restrict__ wmax) {
    __shared__ __align__(16) ushort lds[LDS_TOT];

    const int b   = blockIdx.y;
    const int t0  = blockIdx.x * TT;
    const int tid = threadIdx.x;
    const int l   = tid & 63;
    const int wv  = tid >> 6;
    const int mw  = wv >> 2;                       // M-half (frames 0-31 / 32-63)
    const int nw  = wv & 3;                        // N-set: nf = nw + 4i

    // Issue B-stage for ks=0 first: its latency hides under span staging.
    stageB(wfrag, lds + LDS_B0, 0, wv, l);

    // Stage overlapped span as bf16 with inline reflect padding.
    const float* w = wav + (size_t)b * NSAMP;
    const int g0 = t0 * HOP - (NFFT / 2);
    for (int i = tid; i < SPANU; i += 512) {
        int idx = g0 + i;
        idx = (idx < 0) ? -idx : idx;
        idx = (idx >= NSAMP) ? (2 * NSAMP - 2 - idx) : idx;
        lds[i] = f2bf(w[idx]);
    }
    __syncthreads();   // drains span ds_writes AND stage(0) vmcnt

    f32x4 acc[7][2];
    #pragma unroll
    for (int i = 0; i < 7; ++i)
        #pragma unroll
        for (int m = 0; m < 2; ++m)
            acc[i][m] = (f32x4){0.f, 0.f, 0.f, 0.f};

    const ushort* aRow = lds + (mw * 32 + (l & 15)) * HOP + 8 * (l >> 4);
    int cur = 0;
    for (int ks = 0; ks < KSTEPS; ++ks) {
        if (ks + 1 < KSTEPS)
            stageB(wfrag, lds + LDS_B0 + (cur ^ 1) * BTILE, ks + 1, wv, l);
        const ushort* bbase = lds + LDS_B0 + cur * BTILE + (l << 3);
        const bf16x8 a0 = *reinterpret_cast<const bf16x8*>(aRow + ks * 32);
        const bf16x8 a1 = *reinterpret_cast<const bf16x8*>(aRow + 16 * HOP + ks * 32);
        #pragma unroll
        for (int i = 0; i < 7; ++i) {
            const int nf = nw + 4 * i;
            if (nf < NFRAG) {
                const bf16x8 bf = *reinterpret_cast<const bf16x8*>(bbase + nf * BCHUNK);
                acc[i][0] = __builtin_amdgcn_mfma_f32_16x16x32_bf16(a0, bf, acc[i][0], 0, 0, 0);
                acc[i][1] = __builtin_amdgcn_mfma_f32_16x16x32_bf16(a1, bf, acc[i][1], 0, 0, 0);
            }
        }
        __syncthreads();   // stage(ks+1) drained (overlapped by compute), buf swap safe
        cur ^= 1;
    }

    // pw aliases the B region: all B-reads are complete (barrier above).
    // Zero mel-K padding cols (201..223).
    for (int i = tid; i < TT * 23; i += 512) {
        const int r = i / 23;
        const int c = 201 + i - r * 23;
        lds[LDS_PW + r * PWS + c] = 0;
    }
    // power = re^2+im^2 (adjacent lanes), scatter to pw[frame][freq] as bf16.
    #pragma unroll
    for (int i = 0; i < 7; ++i) {
        const int nf = nw + 4 * i;
        if (nf < NFRAG) {
            #pragma unroll
            for (int m = 0; m < 2; ++m) {
                const f32x4 v = acc[i][m];
                #pragma unroll
                for (int r = 0; r < 4; ++r) {
                    float p = v[r] * v[r];
                    p += __shfl_xor(p, 1);
                    if (!(l & 1)) {
                        const int f = 8 * nf + ((l & 15) >> 1);
                        const int fr = mw * 32 + 16 * m + 4 * (l >> 4) + r;
                        if (f < NFREQ) lds[LDS_PW + fr * PWS + f] = f2bf(p);
                    }
                }
            }
        }
    }
    __syncthreads();

    // Mel GEMM: 20 tiles (Mf 0..4 x ff 0..3); wave wv takes tiles wv, wv+8, wv+16.
    float lmax = -3.0e38f;
    #pragma unroll
    for (int q = 0; q < 3; ++q) {
        const int tile = wv + 8 * q;
        if (tile < 20) {
            const int Mf = tile >> 2;
            const int ff = tile & 3;
            f32x4 mc = (f32x4){0.f, 0.f, 0.f, 0.f};
            #pragma unroll
            for (int ks = 0; ks < MKSTEPS; ++ks) {
                const bf16x8 aT = *reinterpret_cast<const bf16x8*>(
                    mfrag + ((size_t)(Mf * MKSTEPS + ks) * 64 + l) * 8);
                const bf16x8 bP = *reinterpret_cast<const bf16x8*>(
                    lds + LDS_PW + (ff * 16 + (l & 15)) * PWS + 8 * (l >> 4) + 32 * ks);
                mc = __builtin_amdgcn_mfma_f32_16x16x32_bf16(aT, bP, mc, 0, 0, 0);
            }
            #pragma unroll
            for (int r = 0; r < 4; ++r) {
                const int mel = Mf * 16 + 4 * (l >> 4) + r;
                const int frame = t0 + ff * 16 + (l & 15);
                if (frame < NFRAMES) {
                    const float v = log10f(fmaxf(mc[r], 1e-10f));
                    out[((size_t)b * NMELS + mel) * NFRAMES + frame] = v;
                    lmax = fmaxf(lmax, v);
                }
            }
        }
    }

    #pragma unroll
    for (int off = 32; off > 0; off >>= 1)
        lmax = fmaxf(lmax, __shfl_xor(lmax, off));
    if (l == 0) {
        const unsigned bits = __float_as_uint(lmax);
        const unsigned key = bits ^ ((bits & 0x80000000u) ? 0xFFFFFFFFu : 0x80000000u);
        atomicMax(&wmax[b], key);
    }
}

__global__ __launch_bounds__(256)
void finalize_k(float* __restrict__ out, const unsigned* __restrict__ wmax,
                const int* __restrict__ valid) {
    const int i = blockIdx.x * 256 + threadIdx.x;
    if (i < FEAT_ELEMS) {
        const int b = i / (NMELS * NFRAMES);
        const unsigned key = wmax[b];
        const unsigned bits = key ^ ((key & 0x80000000u) ? 0x80000000u : 0xFFFFFFFFu);
        const float mx = __uint_as_float(bits);
        float v = out[i];
        v = fmaxf(v, mx - 8.0f);
        out[i] = (v + 4.0f) * 0.25f;
    } else if (i < OUT_ELEMS) {
        const int j = i - FEAT_ELEMS;
        const int bb = j / NFRAMES;
        const int tf = j - bb * NFRAMES;
        out[i] = (tf * HOP < valid[bb]) ? 1.0f : 0.0f;
    }
}

extern "C" void kernel_launch(void* const* d_in, const int* in_sizes, int n_in,
                              void* d_out, int out_size, void* d_ws, size_t ws_size,
                              hipStream_t stream) {
    const float* wav   = (const float*)d_in[0];
    const int*   valid = (const int*)d_in[1];
    const float* mf    = (const float*)d_in[2];
    float* out = (float*)d_out;

    ushort*   wfrag = (ushort*)d_ws;
    ushort*   mfrag = (ushort*)((char*)d_ws + WFRAG_BYTES);
    unsigned* wmax  = (unsigned*)((char*)d_ws + WFRAG_BYTES + MFRAG_BYTES);

    const int fill_items = WFRAG_ELEMS / 8 + MFRAG_ELEMS / 8;
    fill_tables_k<<<(fill_items + 255) / 256, 256, 0, stream>>>(wfrag, mfrag, mf, wmax);
    dim3 g(TBLK, BATCH);
    stft_mel_mfma_k<<<g, 512, 0, stream>>>(wav, wfrag, mfrag, out, wmax);
    finalize_k<<<(OUT_ELEMS + 255) / 256, 256, 0, stream>>>(out, wmax, valid);
}